// Round 18
// baseline (233.725 us; speedup 1.0000x reference)
//
#include <hip/hip_runtime.h>
#include <math.h>

#define NDIR 5
#define E_ 16
#define W_ 3
#define D_ 128
#define P_ 256
#define B_ 4
#define ROWS 64
#define NPQ 4
#define NT 12        // k64-chunks: W_*P_/64
#define PARTN (B_ * E_ * NPQ * ROWS * D_)   // 2,097,152 elements per x-slice

typedef __attribute__((ext_vector_type(8))) short short8;
typedef __attribute__((ext_vector_type(4))) float f32x4;
typedef __attribute__((ext_vector_type(8))) float f32x8;
typedef __attribute__((ext_vector_type(4))) _Float16 half4;

struct RoutesArg { int r[E_][W_]; };

// Replicates Python _cantor_coord + stable argsort route construction on host.
static RoutesArg make_routes() {
    float coords[E_];
    for (int i = 0; i < E_; ++i) {
        double x = (double)i / (double)(E_ - 1);
        if (x < 1e-6) x = 1e-6;
        if (x > 1.0 - 1e-6) x = 1.0 - 1e-6;
        double val = 0.0, factor = 0.5;
        for (int d = 0; d < 8; ++d) {
            x *= 3.0;
            int digit = (int)x;
            x -= (double)digit;
            if (digit == 2) val += factor;
            factor *= 0.5;
        }
        coords[i] = (float)val;
    }
    RoutesArg R;
    for (int i = 0; i < E_; ++i) {
        float d[E_]; int idx[E_];
        for (int j = 0; j < E_; ++j) { d[j] = fabsf(coords[j] - coords[i]); idx[j] = j; }
        for (int a = 1; a < E_; ++a) {
            int key = idx[a]; float kd = d[key];
            int c = a - 1;
            while (c >= 0 && d[idx[c]] > kd) { idx[c + 1] = idx[c]; --c; }
            idx[c + 1] = key;
        }
        int top[W_] = { idx[0], idx[1], idx[2] };
        if (top[0] > top[1]) { int t = top[0]; top[0] = top[1]; top[1] = t; }
        if (top[1] > top[2]) { int t = top[1]; top[1] = top[2]; top[2] = t; }
        if (top[0] > top[1]) { int t = top[0]; top[0] = top[1]; top[1] = t; }
        for (int w = 0; w < W_; ++w) R.r[i][w] = top[w];
    }
    return R;
}

// exact RNE float->bf16 (finite inputs only)
static __device__ __forceinline__ unsigned short f2bf(float f) {
    union { float f; unsigned int u; } v; v.f = f;
    unsigned int r = (v.u + 0x7FFFu + ((v.u >> 16) & 1u)) >> 16;
    return (unsigned short)r;
}

// HW packed f32->bf16 (RNE), proven correct in Rounds 6/7/12/13/16/17.
static __device__ __forceinline__ unsigned int cvt_pk_bf16(float lo, float hi) {
    unsigned int r;
    asm("v_cvt_pk_bf16_f32 %0, %1, %2" : "=v"(r) : "v"(lo), "v"(hi));
    return r;
}

// By-VALUE vector in, literal indices only -> stays in registers (rule #20).
static __device__ __forceinline__ short8 pack8(f32x8 a) {
    union { unsigned int u[4]; short8 s; } cv;
    cv.u[0] = cvt_pk_bf16(a[0], a[1]);
    cv.u[1] = cvt_pk_bf16(a[2], a[3]);
    cv.u[2] = cvt_pk_bf16(a[4], a[5]);
    cv.u[3] = cvt_pk_bf16(a[6], a[7]);
    return cv.s;
}

// async global->LDS, 16B per lane (dest = wave-uniform base + lane*16)
static __device__ __forceinline__ void gld16(const void* g, void* l) {
    __builtin_amdgcn_global_load_lds(
        (const __attribute__((address_space(1))) unsigned int*)g,
        (__attribute__((address_space(3))) unsigned int*)l,
        16, 0, 0);
}

// ---- prep: V fp32 [slab][k=256][f=128] -> Vt bf16 [slab][f=128][k=256] ----
__global__ __launch_bounds__(256) void vt_prep_kernel(
    const float* __restrict__ V, unsigned short* __restrict__ Vt)
{
    const int sub  = blockIdx.x & 3;          // k-quarter
    const int slab = blockIdx.x >> 2;         // 0..319
    const int tid  = threadIdx.x;
    const float4* __restrict__ src =
        reinterpret_cast<const float4*>(V + (size_t)slab * (P_ * D_));
    unsigned short* __restrict__ dst = Vt + (size_t)slab * (P_ * D_);
    #pragma unroll
    for (int it = 0; it < 8; ++it) {
        const int idx4 = sub * 2048 + it * 256 + tid;
        const int k  = idx4 >> 5;
        const int f4 = (idx4 & 31) * 4;
        const float4 v = src[idx4];
        dst[(size_t)(f4 + 0) * P_ + k] = f2bf(v.x);
        dst[(size_t)(f4 + 1) * P_ + k] = f2bf(v.y);
        dst[(size_t)(f4 + 2) * P_ + k] = f2bf(v.z);
        dst[(size_t)(f4 + 3) * P_ + k] = f2bf(v.w);
    }
}

// Block = (x, e, b, pq-tile of 64 rows); 1280 blocks, 4 waves, 2x2 wave split
// (32-row half x 64-col half). Vt k64-tile [128f][64k] bf16 staged into a
// SINGLE 16KB LDS buffer via global_load_lds (XOR-swizzled source, R17-proven
// addressing, zero bank conflicts). LDS 19.5KB -> 8 blocks/CU (32 waves/CU):
// barrier drains hidden by TLP (m114), not intra-block double-buffering.
// Partials written as fp16 (halves partial+reduce HBM traffic; |v|<=~1).
template <bool ATOMIC>
__global__ __launch_bounds__(256, 8) void cantor_partial3_kernel(
    const float* __restrict__ Q, const float* __restrict__ K,
    const unsigned short* __restrict__ Vt, const float* __restrict__ betas,
    const float* __restrict__ temperature, const float* __restrict__ fusion,
    void* __restrict__ target, RoutesArg routes)
{
    __shared__ float s_lds[W_ * P_];                      // 3 KB
    __shared__ __align__(16) unsigned char vbuf[16384];   // 16 KB (single buf)

    // XCD-bijective swizzle: 1280 blocks = 8 XCDs x 160
    const int orig = blockIdx.x;
    const int wg   = (orig & 7) * 160 + (orig >> 3);

    const int pq = wg & 3;
    const int b  = (wg >> 2) & 3;
    const int e  = (wg >> 4) & 15;
    const int x  = wg >> 8;

    const int tid  = threadIdx.x;
    const int lane = tid & 63;
    const int wv   = tid >> 6;
    const int l15  = lane & 15;
    const int lg   = lane >> 4;

    const int rowbase = (wv >> 1) * 32;   // wave's 32-row half
    const int fhalf   = wv & 1;           // wave's 64-col half

    const float temp = fabsf(temperature[0]) + 1e-6f;

    // fusion softmax -> weight for this x
    float fwx;
    {
        float fv[NDIR], fmx = -1e30f, fsum = 0.f;
        #pragma unroll
        for (int i = 0; i < NDIR; ++i) { fv[i] = fusion[i]; fmx = fmaxf(fmx, fv[i]); }
        #pragma unroll
        for (int i = 0; i < NDIR; ++i) { fv[i] = __expf(fv[i] - fmx); fsum += fv[i]; }
        fwx = fv[x] / fsum;
    }

    int rt[W_]; float bf3[W_];
    #pragma unroll
    for (int w = 0; w < W_; ++w) {
        rt[w] = routes.r[e][w];
        float bv_ = betas[e * E_ + rt[w]];
        bf3[w] = (rt[w] == e) ? 1.0f : 1.0f / (1.0f + __expf(-bv_));
    }

    // stage s = K * beta (768 floats)
    #pragma unroll
    for (int w = 0; w < W_; ++w)
        s_lds[w * P_ + tid] =
            K[(((size_t)(x * E_ + rt[w])) * B_ + b) * P_ + tid] * bf3[w];

    // q rows this lane contributes to
    const float* Qb = Q + (((size_t)(x * E_ + e)) * B_ + b) * P_ + pq * ROWS + rowbase;
    float q2[2];
    q2[0] = Qb[l15] / temp;
    q2[1] = Qb[16 + l15] / temp;

    // Vt slab pointers (bf16 units)
    const unsigned short* vs0 = Vt + ((size_t)(x * E_ + rt[0]) * B_ + b) * (P_ * D_);
    const unsigned short* vs1 = Vt + ((size_t)(x * E_ + rt[1]) * B_ + b) * (P_ * D_);
    const unsigned short* vs2 = Vt + ((size_t)(x * E_ + rt[2]) * B_ + b) * (P_ * D_);

    // ---- stage addressing (R17-proven, zero conflicts) ----
    // lane covers f = wv*8 + (lane>>3) + h*32, 16B chunk j = lane&7;
    // source k-chunk = j ^ (lane>>3)  (inverse-swizzle so LDS is swizzled);
    // dest (wave-uniform) = vbuf + wv*1024 + h*4096, HW adds lane*16.
    const int src_off = (wv * 8 + (lane >> 3)) * P_ + ((lane & 7) ^ (lane >> 3)) * 8;

    // ---- read addressing: byte = f*128 + ((s*4+lg)^(f&7))*16, f = c'*16+l15 ----
    const int rdbase = fhalf * 8192 + l15 * 128 + ((lg ^ (l15 & 7)) * 16);

    #define STAGE(t_) do {                                                       \
        const unsigned short* sl_ = ((t_) >> 2) == 0 ? vs0                       \
                                  : (((t_) >> 2) == 1 ? vs1 : vs2);              \
        const unsigned short* sb_ = sl_ + (((t_) & 3) * 64) + src_off;           \
        char* db_ = (char*)vbuf + wv * 1024;                                     \
        gld16(sb_,          db_);                                                \
        gld16(sb_ +  8192,  db_ + 4096);                                         \
        gld16(sb_ + 16384,  db_ + 8192);                                         \
        gld16(sb_ + 24576,  db_ + 12288);                                        \
    } while (0)

    STAGE(0);
    __syncthreads();   // s_lds visible + chunk 0 landed

    f32x4 acc[2][4];
    #pragma unroll
    for (int fr = 0; fr < 2; ++fr)
        #pragma unroll
        for (int c = 0; c < 4; ++c)
            acc[fr][c] = (f32x4){0.f, 0.f, 0.f, 0.f};
    float den[2] = {0.f, 0.f};

    #pragma unroll 1   // R16 lesson: full unroll -> VGPR blowup -> 1 block/CU
    for (int t = 0; t < NT; ++t) {
        #pragma unroll
        for (int s = 0; s < 2; ++s) {
            // ---- A fragments: 16 exps (s octet broadcast from s_lds) ----
            const float* sp = s_lds + (t >> 2) * P_ + (t & 3) * 64 + s * 32 + 8 * lg;
            f32x8 sv;
            {
                const float4 s0_ = *reinterpret_cast<const float4*>(sp);
                const float4 s1_ = *reinterpret_cast<const float4*>(sp + 4);
                sv[0] = s0_.x; sv[1] = s0_.y; sv[2] = s0_.z; sv[3] = s0_.w;
                sv[4] = s1_.x; sv[5] = s1_.y; sv[6] = s1_.z; sv[7] = s1_.w;
            }
            short8 af0, af1;
            {
                f32x8 e0, e1;
                #pragma unroll
                for (int i = 0; i < 8; ++i) e0[i] = __expf(q2[0] * sv[i]);
                #pragma unroll
                for (int i = 0; i < 8; ++i) e1[i] = __expf(q2[1] * sv[i]);
                den[0] += ((e0[0]+e0[1]) + (e0[2]+e0[3])) + ((e0[4]+e0[5]) + (e0[6]+e0[7]));
                den[1] += ((e1[0]+e1[1]) + (e1[2]+e1[3])) + ((e1[4]+e1[5]) + (e1[6]+e1[7]));
                af0 = pack8(e0);
                af1 = pack8(e1);
            }

            // ---- 4 col-groups: swizzled ds_read_b128 + 2 MFMAs each ----
            #pragma unroll
            for (int c = 0; c < 4; ++c) {
                const short8 bf = *reinterpret_cast<const short8*>(
                    &vbuf[(rdbase ^ (s << 6)) + c * 2048]);
                acc[0][c] = __builtin_amdgcn_mfma_f32_16x16x32_bf16(
                    af0, bf, acc[0][c], 0, 0, 0);
                acc[1][c] = __builtin_amdgcn_mfma_f32_16x16x32_bf16(
                    af1, bf, acc[1][c], 0, 0, 0);
            }
        }
        if (t < NT - 1) {
            __syncthreads();   // everyone done reading vbuf for chunk t
            STAGE(t + 1);
            __syncthreads();   // chunk t+1 landed
        }
    }
    #undef STAGE

    // ---- full-row denominators: sum across the 4 lane-groups ----
    #pragma unroll
    for (int fr = 0; fr < 2; ++fr) {
        den[fr] += __shfl_xor(den[fr], 16);
        den[fr] += __shfl_xor(den[fr], 32);
    }

    // ---- scale + write ----
    const size_t obase = ((((size_t)b * E_ + e) * NPQ) + pq) * (ROWS * D_);

    #pragma unroll
    for (int fr = 0; fr < 2; ++fr) {
        #pragma unroll
        for (int r = 0; r < 4; ++r) {
            const float dr = __shfl(den[fr], 4 * lg + r);   // den of row fr*16+4*lg+r
            const float sc = fwx / dr;
            const int row = rowbase + fr * 16 + 4 * lg + r;
            const size_t off = obase + (size_t)row * D_ + fhalf * 64;
            #pragma unroll
            for (int c = 0; c < 4; ++c) {
                const float v = sc * acc[fr][c][r];
                if (ATOMIC) {
                    atomicAdd((float*)target + off + c * 16 + l15, v);
                } else {
                    _Float16* op = (_Float16*)target + (size_t)x * PARTN + off;
                    op[c * 16 + l15] = (_Float16)v;
                }
            }
        }
    }
}

// sum 5 fp16 partial slices -> fp32 out
__global__ __launch_bounds__(256) void reduce5h_kernel(
    const _Float16* __restrict__ part, float* __restrict__ out)
{
    const size_t i = (size_t)blockIdx.x * 256 + threadIdx.x;   // 4-elem group
    float a0 = 0.f, a1 = 0.f, a2 = 0.f, a3 = 0.f;
    #pragma unroll
    for (int x = 0; x < NDIR; ++x) {
        const half4 h = *reinterpret_cast<const half4*>(part + (size_t)x * PARTN + i * 4);
        a0 += (float)h[0]; a1 += (float)h[1]; a2 += (float)h[2]; a3 += (float)h[3];
    }
    reinterpret_cast<float4*>(out)[i] = make_float4(a0, a1, a2, a3);
}

extern "C" void kernel_launch(void* const* d_in, const int* in_sizes, int n_in,
                              void* d_out, int out_size, void* d_ws, size_t ws_size,
                              hipStream_t stream) {
    (void)in_sizes; (void)n_in;
    RoutesArg R = make_routes();
    const float* Q     = (const float*)d_in[0];
    const float* K     = (const float*)d_in[1];
    const float* V     = (const float*)d_in[2];
    const float* betas = (const float*)d_in[3];
    const float* tempr = (const float*)d_in[4];
    const float* fuse  = (const float*)d_in[5];
    float* out = (float*)d_out;

    const size_t vt_bytes   = (size_t)NDIR * E_ * B_ * P_ * D_ * 2;   // ~21 MB
    const size_t part_bytes = (size_t)NDIR * PARTN * 2;               // ~21 MB (fp16)

    dim3 grid(NDIR * E_ * B_ * NPQ);   // 1280
    dim3 block(256);

    if (ws_size >= vt_bytes + part_bytes) {
        unsigned short* Vt = (unsigned short*)d_ws;
        _Float16* part = (_Float16*)((char*)d_ws + vt_bytes);
        hipLaunchKernelGGL(vt_prep_kernel, dim3(1280), block, 0, stream, V, Vt);
        hipLaunchKernelGGL((cantor_partial3_kernel<false>), grid, block, 0, stream,
                           Q, K, Vt, betas, tempr, fuse, (void*)part, R);
        hipLaunchKernelGGL(reduce5h_kernel, dim3(2048), block, 0, stream,
                           part, out);
    } else {
        unsigned short* Vt = (unsigned short*)d_ws;   // ws >= 21MB always observed
        (void)hipMemsetAsync(d_out, 0, (size_t)out_size * 4, stream);
        hipLaunchKernelGGL(vt_prep_kernel, dim3(1280), block, 0, stream, V, Vt);
        hipLaunchKernelGGL((cantor_partial3_kernel<true>), grid, block, 0, stream,
                           Q, K, Vt, betas, tempr, fuse, (void*)out, R);
    }
}

// Round 19
// 74.715 us; speedup vs baseline: 3.1282x; 3.1282x over previous
//
#include <hip/hip_runtime.h>
#include <math.h>

#define NDIR 5
#define E_ 16
#define W_ 3
#define D_ 128
#define P_ 256
#define B_ 4
#define ROWS 64
#define NPQ 4
#define NT 12        // k64-chunks: W_*P_/64
#define PARTN (B_ * E_ * NPQ * ROWS * D_)   // 2,097,152 elements per x-slice

typedef __attribute__((ext_vector_type(8))) short short8;
typedef __attribute__((ext_vector_type(4))) float f32x4;
typedef __attribute__((ext_vector_type(8))) float f32x8;
typedef __attribute__((ext_vector_type(4))) _Float16 half4;

struct RoutesArg { int r[E_][W_]; };

// Replicates Python _cantor_coord + stable argsort route construction on host.
static RoutesArg make_routes() {
    float coords[E_];
    for (int i = 0; i < E_; ++i) {
        double x = (double)i / (double)(E_ - 1);
        if (x < 1e-6) x = 1e-6;
        if (x > 1.0 - 1e-6) x = 1.0 - 1e-6;
        double val = 0.0, factor = 0.5;
        for (int d = 0; d < 8; ++d) {
            x *= 3.0;
            int digit = (int)x;
            x -= (double)digit;
            if (digit == 2) val += factor;
            factor *= 0.5;
        }
        coords[i] = (float)val;
    }
    RoutesArg R;
    for (int i = 0; i < E_; ++i) {
        float d[E_]; int idx[E_];
        for (int j = 0; j < E_; ++j) { d[j] = fabsf(coords[j] - coords[i]); idx[j] = j; }
        for (int a = 1; a < E_; ++a) {
            int key = idx[a]; float kd = d[key];
            int c = a - 1;
            while (c >= 0 && d[idx[c]] > kd) { idx[c + 1] = idx[c]; --c; }
            idx[c + 1] = key;
        }
        int top[W_] = { idx[0], idx[1], idx[2] };
        if (top[0] > top[1]) { int t = top[0]; top[0] = top[1]; top[1] = t; }
        if (top[1] > top[2]) { int t = top[1]; top[1] = top[2]; top[2] = t; }
        if (top[0] > top[1]) { int t = top[0]; top[0] = top[1]; top[1] = t; }
        for (int w = 0; w < W_; ++w) R.r[i][w] = top[w];
    }
    return R;
}

// exact RNE float->bf16 (finite inputs only)
static __device__ __forceinline__ unsigned short f2bf(float f) {
    union { float f; unsigned int u; } v; v.f = f;
    unsigned int r = (v.u + 0x7FFFu + ((v.u >> 16) & 1u)) >> 16;
    return (unsigned short)r;
}

// HW packed f32->bf16 (RNE), proven correct in Rounds 6/7/12/13/16/17/18.
static __device__ __forceinline__ unsigned int cvt_pk_bf16(float lo, float hi) {
    unsigned int r;
    asm("v_cvt_pk_bf16_f32 %0, %1, %2" : "=v"(r) : "v"(lo), "v"(hi));
    return r;
}

// By-VALUE vector in, literal indices only -> stays in registers (rule #20).
static __device__ __forceinline__ short8 pack8(f32x8 a) {
    union { unsigned int u[4]; short8 s; } cv;
    cv.u[0] = cvt_pk_bf16(a[0], a[1]);
    cv.u[1] = cvt_pk_bf16(a[2], a[3]);
    cv.u[2] = cvt_pk_bf16(a[4], a[5]);
    cv.u[3] = cvt_pk_bf16(a[6], a[7]);
    return cv.s;
}

// async global->LDS, 16B per lane (dest = wave-uniform base + lane*16)
static __device__ __forceinline__ void gld16(const void* g, void* l) {
    __builtin_amdgcn_global_load_lds(
        (const __attribute__((address_space(1))) unsigned int*)g,
        (__attribute__((address_space(3))) unsigned int*)l,
        16, 0, 0);
}

// ---- prep: V fp32 [slab][k=256][f=128] -> Vt bf16 [slab][f=128][k=256] ----
__global__ __launch_bounds__(256) void vt_prep_kernel(
    const float* __restrict__ V, unsigned short* __restrict__ Vt)
{
    const int sub  = blockIdx.x & 3;          // k-quarter
    const int slab = blockIdx.x >> 2;         // 0..319
    const int tid  = threadIdx.x;
    const float4* __restrict__ src =
        reinterpret_cast<const float4*>(V + (size_t)slab * (P_ * D_));
    unsigned short* __restrict__ dst = Vt + (size_t)slab * (P_ * D_);
    #pragma unroll
    for (int it = 0; it < 8; ++it) {
        const int idx4 = sub * 2048 + it * 256 + tid;
        const int k  = idx4 >> 5;
        const int f4 = (idx4 & 31) * 4;
        const float4 v = src[idx4];
        dst[(size_t)(f4 + 0) * P_ + k] = f2bf(v.x);
        dst[(size_t)(f4 + 1) * P_ + k] = f2bf(v.y);
        dst[(size_t)(f4 + 2) * P_ + k] = f2bf(v.z);
        dst[(size_t)(f4 + 3) * P_ + k] = f2bf(v.w);
    }
}

// Block = (x, e, b, pq-tile of 64 rows); 1280 blocks, 4 waves, 2x2 wave split
// (32-row half x 64-col half). Vt k64-tile [128f][64k] bf16 staged into a
// SINGLE 16KB LDS buffer via global_load_lds (XOR-swizzled source, R17-proven
// addressing, zero bank conflicts). LDS 19.5KB allows up to 8 blocks/CU;
// launch_bounds(256,4) (NOT 8 — R18: min-waves 8 capped VGPR at ~64 -> full
// accumulator spill, 345MB scratch fetch, 3x slower) keeps the R17-proven
// 52-VGPR no-spill allocation while letting HW schedule extra blocks.
// Partials written as fp16 (halves partial+reduce HBM traffic; |v|<=~1).
template <bool ATOMIC>
__global__ __launch_bounds__(256, 4) void cantor_partial3_kernel(
    const float* __restrict__ Q, const float* __restrict__ K,
    const unsigned short* __restrict__ Vt, const float* __restrict__ betas,
    const float* __restrict__ temperature, const float* __restrict__ fusion,
    void* __restrict__ target, RoutesArg routes)
{
    __shared__ float s_lds[W_ * P_];                      // 3 KB
    __shared__ __align__(16) unsigned char vbuf[16384];   // 16 KB (single buf)

    // XCD-bijective swizzle: 1280 blocks = 8 XCDs x 160
    const int orig = blockIdx.x;
    const int wg   = (orig & 7) * 160 + (orig >> 3);

    const int pq = wg & 3;
    const int b  = (wg >> 2) & 3;
    const int e  = (wg >> 4) & 15;
    const int x  = wg >> 8;

    const int tid  = threadIdx.x;
    const int lane = tid & 63;
    const int wv   = tid >> 6;
    const int l15  = lane & 15;
    const int lg   = lane >> 4;

    const int rowbase = (wv >> 1) * 32;   // wave's 32-row half
    const int fhalf   = wv & 1;           // wave's 64-col half

    const float temp = fabsf(temperature[0]) + 1e-6f;

    // fusion softmax -> weight for this x
    float fwx;
    {
        float fv[NDIR], fmx = -1e30f, fsum = 0.f;
        #pragma unroll
        for (int i = 0; i < NDIR; ++i) { fv[i] = fusion[i]; fmx = fmaxf(fmx, fv[i]); }
        #pragma unroll
        for (int i = 0; i < NDIR; ++i) { fv[i] = __expf(fv[i] - fmx); fsum += fv[i]; }
        fwx = fv[x] / fsum;
    }

    int rt[W_]; float bf3[W_];
    #pragma unroll
    for (int w = 0; w < W_; ++w) {
        rt[w] = routes.r[e][w];
        float bv_ = betas[e * E_ + rt[w]];
        bf3[w] = (rt[w] == e) ? 1.0f : 1.0f / (1.0f + __expf(-bv_));
    }

    // stage s = K * beta (768 floats)
    #pragma unroll
    for (int w = 0; w < W_; ++w)
        s_lds[w * P_ + tid] =
            K[(((size_t)(x * E_ + rt[w])) * B_ + b) * P_ + tid] * bf3[w];

    // q rows this lane contributes to
    const float* Qb = Q + (((size_t)(x * E_ + e)) * B_ + b) * P_ + pq * ROWS + rowbase;
    float q2[2];
    q2[0] = Qb[l15] / temp;
    q2[1] = Qb[16 + l15] / temp;

    // Vt slab pointers (bf16 units)
    const unsigned short* vs0 = Vt + ((size_t)(x * E_ + rt[0]) * B_ + b) * (P_ * D_);
    const unsigned short* vs1 = Vt + ((size_t)(x * E_ + rt[1]) * B_ + b) * (P_ * D_);
    const unsigned short* vs2 = Vt + ((size_t)(x * E_ + rt[2]) * B_ + b) * (P_ * D_);

    // ---- stage addressing (R17-proven, zero conflicts) ----
    // lane covers f = wv*8 + (lane>>3) + h*32, 16B chunk j = lane&7;
    // source k-chunk = j ^ (lane>>3)  (inverse-swizzle so LDS is swizzled);
    // dest (wave-uniform) = vbuf + wv*1024 + h*4096, HW adds lane*16.
    const int src_off = (wv * 8 + (lane >> 3)) * P_ + ((lane & 7) ^ (lane >> 3)) * 8;

    // ---- read addressing: byte = f*128 + ((s*4+lg)^(f&7))*16, f = c'*16+l15 ----
    const int rdbase = fhalf * 8192 + l15 * 128 + ((lg ^ (l15 & 7)) * 16);

    #define STAGE(t_) do {                                                       \
        const unsigned short* sl_ = ((t_) >> 2) == 0 ? vs0                       \
                                  : (((t_) >> 2) == 1 ? vs1 : vs2);              \
        const unsigned short* sb_ = sl_ + (((t_) & 3) * 64) + src_off;           \
        char* db_ = (char*)vbuf + wv * 1024;                                     \
        gld16(sb_,          db_);                                                \
        gld16(sb_ +  8192,  db_ + 4096);                                         \
        gld16(sb_ + 16384,  db_ + 8192);                                         \
        gld16(sb_ + 24576,  db_ + 12288);                                        \
    } while (0)

    STAGE(0);
    __syncthreads();   // s_lds visible + chunk 0 landed

    f32x4 acc[2][4];
    #pragma unroll
    for (int fr = 0; fr < 2; ++fr)
        #pragma unroll
        for (int c = 0; c < 4; ++c)
            acc[fr][c] = (f32x4){0.f, 0.f, 0.f, 0.f};
    float den[2] = {0.f, 0.f};

    #pragma unroll 1   // R16 lesson: full unroll -> VGPR blowup -> 1 block/CU
    for (int t = 0; t < NT; ++t) {
        #pragma unroll
        for (int s = 0; s < 2; ++s) {
            // ---- A fragments: 16 exps (s octet broadcast from s_lds) ----
            const float* sp = s_lds + (t >> 2) * P_ + (t & 3) * 64 + s * 32 + 8 * lg;
            f32x8 sv;
            {
                const float4 s0_ = *reinterpret_cast<const float4*>(sp);
                const float4 s1_ = *reinterpret_cast<const float4*>(sp + 4);
                sv[0] = s0_.x; sv[1] = s0_.y; sv[2] = s0_.z; sv[3] = s0_.w;
                sv[4] = s1_.x; sv[5] = s1_.y; sv[6] = s1_.z; sv[7] = s1_.w;
            }
            short8 af0, af1;
            {
                f32x8 e0, e1;
                #pragma unroll
                for (int i = 0; i < 8; ++i) e0[i] = __expf(q2[0] * sv[i]);
                #pragma unroll
                for (int i = 0; i < 8; ++i) e1[i] = __expf(q2[1] * sv[i]);
                den[0] += ((e0[0]+e0[1]) + (e0[2]+e0[3])) + ((e0[4]+e0[5]) + (e0[6]+e0[7]));
                den[1] += ((e1[0]+e1[1]) + (e1[2]+e1[3])) + ((e1[4]+e1[5]) + (e1[6]+e1[7]));
                af0 = pack8(e0);
                af1 = pack8(e1);
            }

            // ---- 4 col-groups: swizzled ds_read_b128 + 2 MFMAs each ----
            #pragma unroll
            for (int c = 0; c < 4; ++c) {
                const short8 bf = *reinterpret_cast<const short8*>(
                    &vbuf[(rdbase ^ (s << 6)) + c * 2048]);
                acc[0][c] = __builtin_amdgcn_mfma_f32_16x16x32_bf16(
                    af0, bf, acc[0][c], 0, 0, 0);
                acc[1][c] = __builtin_amdgcn_mfma_f32_16x16x32_bf16(
                    af1, bf, acc[1][c], 0, 0, 0);
            }
        }
        if (t < NT - 1) {
            __syncthreads();   // everyone done reading vbuf for chunk t
            STAGE(t + 1);
            __syncthreads();   // chunk t+1 landed
        }
    }
    #undef STAGE

    // ---- full-row denominators: sum across the 4 lane-groups ----
    #pragma unroll
    for (int fr = 0; fr < 2; ++fr) {
        den[fr] += __shfl_xor(den[fr], 16);
        den[fr] += __shfl_xor(den[fr], 32);
    }

    // ---- scale + write ----
    const size_t obase = ((((size_t)b * E_ + e) * NPQ) + pq) * (ROWS * D_);

    #pragma unroll
    for (int fr = 0; fr < 2; ++fr) {
        #pragma unroll
        for (int r = 0; r < 4; ++r) {
            const float dr = __shfl(den[fr], 4 * lg + r);   // den of row fr*16+4*lg+r
            const float sc = fwx / dr;
            const int row = rowbase + fr * 16 + 4 * lg + r;
            const size_t off = obase + (size_t)row * D_ + fhalf * 64;
            #pragma unroll
            for (int c = 0; c < 4; ++c) {
                const float v = sc * acc[fr][c][r];
                if (ATOMIC) {
                    atomicAdd((float*)target + off + c * 16 + l15, v);
                } else {
                    _Float16* op = (_Float16*)target + (size_t)x * PARTN + off;
                    op[c * 16 + l15] = (_Float16)v;
                }
            }
        }
    }
}

// sum 5 fp16 partial slices -> fp32 out
__global__ __launch_bounds__(256) void reduce5h_kernel(
    const _Float16* __restrict__ part, float* __restrict__ out)
{
    const size_t i = (size_t)blockIdx.x * 256 + threadIdx.x;   // 4-elem group
    float a0 = 0.f, a1 = 0.f, a2 = 0.f, a3 = 0.f;
    #pragma unroll
    for (int x = 0; x < NDIR; ++x) {
        const half4 h = *reinterpret_cast<const half4*>(part + (size_t)x * PARTN + i * 4);
        a0 += (float)h[0]; a1 += (float)h[1]; a2 += (float)h[2]; a3 += (float)h[3];
    }
    reinterpret_cast<float4*>(out)[i] = make_float4(a0, a1, a2, a3);
}

extern "C" void kernel_launch(void* const* d_in, const int* in_sizes, int n_in,
                              void* d_out, int out_size, void* d_ws, size_t ws_size,
                              hipStream_t stream) {
    (void)in_sizes; (void)n_in;
    RoutesArg R = make_routes();
    const float* Q     = (const float*)d_in[0];
    const float* K     = (const float*)d_in[1];
    const float* V     = (const float*)d_in[2];
    const float* betas = (const float*)d_in[3];
    const float* tempr = (const float*)d_in[4];
    const float* fuse  = (const float*)d_in[5];
    float* out = (float*)d_out;

    const size_t vt_bytes   = (size_t)NDIR * E_ * B_ * P_ * D_ * 2;   // ~21 MB
    const size_t part_bytes = (size_t)NDIR * PARTN * 2;               // ~21 MB (fp16)

    dim3 grid(NDIR * E_ * B_ * NPQ);   // 1280
    dim3 block(256);

    if (ws_size >= vt_bytes + part_bytes) {
        unsigned short* Vt = (unsigned short*)d_ws;
        _Float16* part = (_Float16*)((char*)d_ws + vt_bytes);
        hipLaunchKernelGGL(vt_prep_kernel, dim3(1280), block, 0, stream, V, Vt);
        hipLaunchKernelGGL((cantor_partial3_kernel<false>), grid, block, 0, stream,
                           Q, K, Vt, betas, tempr, fuse, (void*)part, R);
        hipLaunchKernelGGL(reduce5h_kernel, dim3(2048), block, 0, stream,
                           part, out);
    } else {
        unsigned short* Vt = (unsigned short*)d_ws;   // ws >= 21MB always observed
        (void)hipMemsetAsync(d_out, 0, (size_t)out_size * 4, stream);
        hipLaunchKernelGGL(vt_prep_kernel, dim3(1280), block, 0, stream, V, Vt);
        hipLaunchKernelGGL((cantor_partial3_kernel<true>), grid, block, 0, stream,
                           Q, K, Vt, betas, tempr, fuse, (void*)out, R);
    }
}

// Round 20
// 56.447 us; speedup vs baseline: 4.1406x; 1.3236x over previous
//
#include <hip/hip_runtime.h>
#include <math.h>

#define NDIR 5
#define E_ 16
#define W_ 3
#define D_ 128
#define P_ 256
#define B_ 4
#define ROWS 64
#define NPQ 4
#define NT 12        // k64-chunks: W_*P_/64
#define PARTN (B_ * E_ * NPQ * ROWS * D_)   // 2,097,152 elements per x-slice

typedef __attribute__((ext_vector_type(8))) short short8;
typedef __attribute__((ext_vector_type(4))) float f32x4;
typedef __attribute__((ext_vector_type(8))) float f32x8;
typedef __attribute__((ext_vector_type(4))) _Float16 half4;

struct RoutesArg { int r[E_][W_]; };

// Replicates Python _cantor_coord + stable argsort route construction on host.
static RoutesArg make_routes() {
    float coords[E_];
    for (int i = 0; i < E_; ++i) {
        double x = (double)i / (double)(E_ - 1);
        if (x < 1e-6) x = 1e-6;
        if (x > 1.0 - 1e-6) x = 1.0 - 1e-6;
        double val = 0.0, factor = 0.5;
        for (int d = 0; d < 8; ++d) {
            x *= 3.0;
            int digit = (int)x;
            x -= (double)digit;
            if (digit == 2) val += factor;
            factor *= 0.5;
        }
        coords[i] = (float)val;
    }
    RoutesArg R;
    for (int i = 0; i < E_; ++i) {
        float d[E_]; int idx[E_];
        for (int j = 0; j < E_; ++j) { d[j] = fabsf(coords[j] - coords[i]); idx[j] = j; }
        for (int a = 1; a < E_; ++a) {
            int key = idx[a]; float kd = d[key];
            int c = a - 1;
            while (c >= 0 && d[idx[c]] > kd) { idx[c + 1] = idx[c]; --c; }
            idx[c + 1] = key;
        }
        int top[W_] = { idx[0], idx[1], idx[2] };
        if (top[0] > top[1]) { int t = top[0]; top[0] = top[1]; top[1] = t; }
        if (top[1] > top[2]) { int t = top[1]; top[1] = top[2]; top[2] = t; }
        if (top[0] > top[1]) { int t = top[0]; top[0] = top[1]; top[1] = t; }
        for (int w = 0; w < W_; ++w) R.r[i][w] = top[w];
    }
    return R;
}

// exact RNE float->bf16 (finite inputs only)
static __device__ __forceinline__ unsigned short f2bf(float f) {
    union { float f; unsigned int u; } v; v.f = f;
    unsigned int r = (v.u + 0x7FFFu + ((v.u >> 16) & 1u)) >> 16;
    return (unsigned short)r;
}

// HW packed f32->bf16 (RNE), proven correct in Rounds 6/7/12/13/16-19.
static __device__ __forceinline__ unsigned int cvt_pk_bf16(float lo, float hi) {
    unsigned int r;
    asm("v_cvt_pk_bf16_f32 %0, %1, %2" : "=v"(r) : "v"(lo), "v"(hi));
    return r;
}

// By-VALUE vector in, literal indices only -> stays in registers (rule #20).
static __device__ __forceinline__ short8 pack8(f32x8 a) {
    union { unsigned int u[4]; short8 s; } cv;
    cv.u[0] = cvt_pk_bf16(a[0], a[1]);
    cv.u[1] = cvt_pk_bf16(a[2], a[3]);
    cv.u[2] = cvt_pk_bf16(a[4], a[5]);
    cv.u[3] = cvt_pk_bf16(a[6], a[7]);
    return cv.s;
}

// async global->LDS, 16B per lane (dest = wave-uniform base + lane*16)
static __device__ __forceinline__ void gld16(const void* g, void* l) {
    __builtin_amdgcn_global_load_lds(
        (const __attribute__((address_space(1))) unsigned int*)g,
        (__attribute__((address_space(3))) unsigned int*)l,
        16, 0, 0);
}

// ---- prep: V fp32 [slab][k=256][f=128] -> Vt bf16 [slab][f=128][k=256] ----
// LDS-tiled transpose: both global read and write are 16B/lane coalesced
// (R19's version wrote 4 ushorts at 512B stride -> 64 scatter txns/wave).
__global__ __launch_bounds__(256) void vt_prep_kernel(
    const float* __restrict__ V, unsigned short* __restrict__ Vt)
{
    __shared__ unsigned short tl[32][80];   // [f][k64], stride 160B (16B-mult)

    const int slab = blockIdx.x >> 2;       // 0..319
    const int kq   = blockIdx.x & 3;        // k-quarter (64 k's)
    const int tid  = threadIdx.x;

    const float* src = V + (size_t)slab * (P_ * D_) + (size_t)(kq * 64) * D_;
    unsigned short* dst = Vt + (size_t)slab * (P_ * D_) + kq * 64;

    #pragma unroll
    for (int ft = 0; ft < 4; ++ft) {
        const int f0 = ft * 32;
        if (ft) __syncthreads();   // protect tl from previous read phase
        #pragma unroll
        for (int it = 0; it < 2; ++it) {
            const int idx = it * 256 + tid;
            const int kk  = idx >> 3;        // 0..63
            const int fg  = idx & 7;         // float4 group within 32 f
            const float4 v = *reinterpret_cast<const float4*>(
                src + (size_t)kk * D_ + f0 + fg * 4);
            tl[fg * 4 + 0][kk] = f2bf(v.x);
            tl[fg * 4 + 1][kk] = f2bf(v.y);
            tl[fg * 4 + 2][kk] = f2bf(v.z);
            tl[fg * 4 + 3][kk] = f2bf(v.w);
        }
        __syncthreads();
        {
            const int f  = tid >> 3;         // 0..31
            const int kg = tid & 7;          // 16B group of k
            const uint4 val = *reinterpret_cast<const uint4*>(&tl[f][kg * 8]);
            *reinterpret_cast<uint4*>(&dst[(size_t)(f0 + f) * P_ + kg * 8]) = val;
        }
    }
}

// Block = (x, e, b, pq-tile of 64 rows); 1280 blocks, 4 waves, 2x2 wave split
// (32-row half x 64-col half). Vt k64-tile [128f][64k] bf16 staged into a
// SINGLE 16KB LDS buffer via global_load_lds (XOR-swizzled source, R17-proven
// addressing, zero bank conflicts). One barrier-pair per chunk.
// PHASE-STAGGER (new): each block starts its chunk walk at phase=orig%NT and
// wraps — co-resident blocks then hit stage/drain/compute phases out of step,
// so one block's vmcnt drain overlaps another's exp/MFMA burst (anti-convoy).
// Sum over chunks commutes (den/acc fp32 adds) -> ~1ulp reorder noise only.
// launch_bounds(256,4): R18's (256,8) capped VGPR at 64 -> acc spill, 3x slower.
template <bool ATOMIC>
__global__ __launch_bounds__(256, 4) void cantor_partial3_kernel(
    const float* __restrict__ Q, const float* __restrict__ K,
    const unsigned short* __restrict__ Vt, const float* __restrict__ betas,
    const float* __restrict__ temperature, const float* __restrict__ fusion,
    void* __restrict__ target, RoutesArg routes)
{
    __shared__ float s_lds[W_ * P_];                      // 3 KB
    __shared__ __align__(16) unsigned char vbuf[16384];   // 16 KB (single buf)

    // XCD-bijective swizzle: 1280 blocks = 8 XCDs x 160
    const int orig = blockIdx.x;
    const int wg   = (orig & 7) * 160 + (orig >> 3);

    const int pq = wg & 3;
    const int b  = (wg >> 2) & 3;
    const int e  = (wg >> 4) & 15;
    const int x  = wg >> 8;

    const int tid  = threadIdx.x;
    const int lane = tid & 63;
    const int wv   = tid >> 6;
    const int l15  = lane & 15;
    const int lg   = lane >> 4;

    const int rowbase = (wv >> 1) * 32;   // wave's 32-row half
    const int fhalf   = wv & 1;           // wave's 64-col half

    const int phase = orig % NT;          // anti-convoy start offset

    const float temp = fabsf(temperature[0]) + 1e-6f;

    // fusion softmax -> weight for this x
    float fwx;
    {
        float fv[NDIR], fmx = -1e30f, fsum = 0.f;
        #pragma unroll
        for (int i = 0; i < NDIR; ++i) { fv[i] = fusion[i]; fmx = fmaxf(fmx, fv[i]); }
        #pragma unroll
        for (int i = 0; i < NDIR; ++i) { fv[i] = __expf(fv[i] - fmx); fsum += fv[i]; }
        fwx = fv[x] / fsum;
    }

    int rt[W_]; float bf3[W_];
    #pragma unroll
    for (int w = 0; w < W_; ++w) {
        rt[w] = routes.r[e][w];
        float bv_ = betas[e * E_ + rt[w]];
        bf3[w] = (rt[w] == e) ? 1.0f : 1.0f / (1.0f + __expf(-bv_));
    }

    // stage s = K * beta (768 floats)
    #pragma unroll
    for (int w = 0; w < W_; ++w)
        s_lds[w * P_ + tid] =
            K[(((size_t)(x * E_ + rt[w])) * B_ + b) * P_ + tid] * bf3[w];

    // q rows this lane contributes to
    const float* Qb = Q + (((size_t)(x * E_ + e)) * B_ + b) * P_ + pq * ROWS + rowbase;
    float q2[2];
    q2[0] = Qb[l15] / temp;
    q2[1] = Qb[16 + l15] / temp;

    // Vt slab pointers (bf16 units)
    const unsigned short* vs0 = Vt + ((size_t)(x * E_ + rt[0]) * B_ + b) * (P_ * D_);
    const unsigned short* vs1 = Vt + ((size_t)(x * E_ + rt[1]) * B_ + b) * (P_ * D_);
    const unsigned short* vs2 = Vt + ((size_t)(x * E_ + rt[2]) * B_ + b) * (P_ * D_);

    // ---- stage addressing (R17-proven, zero conflicts) ----
    const int src_off = (wv * 8 + (lane >> 3)) * P_ + ((lane & 7) ^ (lane >> 3)) * 8;

    // ---- read addressing: byte = f*128 + ((s*4+lg)^(f&7))*16, f = c'*16+l15 ----
    const int rdbase = fhalf * 8192 + l15 * 128 + ((lg ^ (l15 & 7)) * 16);

    #define STAGE(t_) do {                                                       \
        const unsigned short* sl_ = ((t_) >> 2) == 0 ? vs0                       \
                                  : (((t_) >> 2) == 1 ? vs1 : vs2);              \
        const unsigned short* sb_ = sl_ + (((t_) & 3) * 64) + src_off;           \
        char* db_ = (char*)vbuf + wv * 1024;                                     \
        gld16(sb_,          db_);                                                \
        gld16(sb_ +  8192,  db_ + 4096);                                         \
        gld16(sb_ + 16384,  db_ + 8192);                                         \
        gld16(sb_ + 24576,  db_ + 12288);                                        \
    } while (0)

    STAGE(phase);
    __syncthreads();   // s_lds visible + first chunk landed

    f32x4 acc[2][4];
    #pragma unroll
    for (int fr = 0; fr < 2; ++fr)
        #pragma unroll
        for (int c = 0; c < 4; ++c)
            acc[fr][c] = (f32x4){0.f, 0.f, 0.f, 0.f};
    float den[2] = {0.f, 0.f};

    #pragma unroll 1   // R16 lesson: full unroll -> VGPR blowup -> 1 block/CU
    for (int tt = 0; tt < NT; ++tt) {
        int t = tt + phase;
        if (t >= NT) t -= NT;

        #pragma unroll
        for (int s = 0; s < 2; ++s) {
            // ---- A fragments: 16 exps (s octet broadcast from s_lds) ----
            const float* sp = s_lds + (t >> 2) * P_ + (t & 3) * 64 + s * 32 + 8 * lg;
            f32x8 sv;
            {
                const float4 s0_ = *reinterpret_cast<const float4*>(sp);
                const float4 s1_ = *reinterpret_cast<const float4*>(sp + 4);
                sv[0] = s0_.x; sv[1] = s0_.y; sv[2] = s0_.z; sv[3] = s0_.w;
                sv[4] = s1_.x; sv[5] = s1_.y; sv[6] = s1_.z; sv[7] = s1_.w;
            }
            short8 af0, af1;
            {
                f32x8 e0, e1;
                #pragma unroll
                for (int i = 0; i < 8; ++i) e0[i] = __expf(q2[0] * sv[i]);
                #pragma unroll
                for (int i = 0; i < 8; ++i) e1[i] = __expf(q2[1] * sv[i]);
                den[0] += ((e0[0]+e0[1]) + (e0[2]+e0[3])) + ((e0[4]+e0[5]) + (e0[6]+e0[7]));
                den[1] += ((e1[0]+e1[1]) + (e1[2]+e1[3])) + ((e1[4]+e1[5]) + (e1[6]+e1[7]));
                af0 = pack8(e0);
                af1 = pack8(e1);
            }

            // ---- 4 col-groups: swizzled ds_read_b128 + 2 MFMAs each ----
            #pragma unroll
            for (int c = 0; c < 4; ++c) {
                const short8 bf = *reinterpret_cast<const short8*>(
                    &vbuf[(rdbase ^ (s << 6)) + c * 2048]);
                acc[0][c] = __builtin_amdgcn_mfma_f32_16x16x32_bf16(
                    af0, bf, acc[0][c], 0, 0, 0);
                acc[1][c] = __builtin_amdgcn_mfma_f32_16x16x32_bf16(
                    af1, bf, acc[1][c], 0, 0, 0);
            }
        }
        if (tt < NT - 1) {
            int tn = t + 1;
            if (tn >= NT) tn -= NT;
            __syncthreads();   // everyone done reading vbuf for chunk t
            STAGE(tn);
            __syncthreads();   // next chunk landed
        }
    }
    #undef STAGE

    // ---- full-row denominators: sum across the 4 lane-groups ----
    #pragma unroll
    for (int fr = 0; fr < 2; ++fr) {
        den[fr] += __shfl_xor(den[fr], 16);
        den[fr] += __shfl_xor(den[fr], 32);
    }

    // ---- scale + write ----
    const size_t obase = ((((size_t)b * E_ + e) * NPQ) + pq) * (ROWS * D_);

    #pragma unroll
    for (int fr = 0; fr < 2; ++fr) {
        #pragma unroll
        for (int r = 0; r < 4; ++r) {
            const float dr = __shfl(den[fr], 4 * lg + r);   // den of row fr*16+4*lg+r
            const float sc = fwx / dr;
            const int row = rowbase + fr * 16 + 4 * lg + r;
            const size_t off = obase + (size_t)row * D_ + fhalf * 64;
            #pragma unroll
            for (int c = 0; c < 4; ++c) {
                const float v = sc * acc[fr][c][r];
                if (ATOMIC) {
                    atomicAdd((float*)target + off + c * 16 + l15, v);
                } else {
                    _Float16* op = (_Float16*)target + (size_t)x * PARTN + off;
                    op[c * 16 + l15] = (_Float16)v;
                }
            }
        }
    }
}

// sum 5 fp16 partial slices -> fp32 out
__global__ __launch_bounds__(256) void reduce5h_kernel(
    const _Float16* __restrict__ part, float* __restrict__ out)
{
    const size_t i = (size_t)blockIdx.x * 256 + threadIdx.x;   // 4-elem group
    float a0 = 0.f, a1 = 0.f, a2 = 0.f, a3 = 0.f;
    #pragma unroll
    for (int x = 0; x < NDIR; ++x) {
        const half4 h = *reinterpret_cast<const half4*>(part + (size_t)x * PARTN + i * 4);
        a0 += (float)h[0]; a1 += (float)h[1]; a2 += (float)h[2]; a3 += (float)h[3];
    }
    reinterpret_cast<float4*>(out)[i] = make_float4(a0, a1, a2, a3);
}

extern "C" void kernel_launch(void* const* d_in, const int* in_sizes, int n_in,
                              void* d_out, int out_size, void* d_ws, size_t ws_size,
                              hipStream_t stream) {
    (void)in_sizes; (void)n_in;
    RoutesArg R = make_routes();
    const float* Q     = (const float*)d_in[0];
    const float* K     = (const float*)d_in[1];
    const float* V     = (const float*)d_in[2];
    const float* betas = (const float*)d_in[3];
    const float* tempr = (const float*)d_in[4];
    const float* fuse  = (const float*)d_in[5];
    float* out = (float*)d_out;

    const size_t vt_bytes   = (size_t)NDIR * E_ * B_ * P_ * D_ * 2;   // ~21 MB
    const size_t part_bytes = (size_t)NDIR * PARTN * 2;               // ~21 MB (fp16)

    dim3 grid(NDIR * E_ * B_ * NPQ);   // 1280
    dim3 block(256);

    if (ws_size >= vt_bytes + part_bytes) {
        unsigned short* Vt = (unsigned short*)d_ws;
        _Float16* part = (_Float16*)((char*)d_ws + vt_bytes);
        hipLaunchKernelGGL(vt_prep_kernel, dim3(1280), block, 0, stream, V, Vt);
        hipLaunchKernelGGL((cantor_partial3_kernel<false>), grid, block, 0, stream,
                           Q, K, Vt, betas, tempr, fuse, (void*)part, R);
        hipLaunchKernelGGL(reduce5h_kernel, dim3(2048), block, 0, stream,
                           part, out);
    } else {
        unsigned short* Vt = (unsigned short*)d_ws;   // ws >= 21MB always observed
        (void)hipMemsetAsync(d_out, 0, (size_t)out_size * 4, stream);
        hipLaunchKernelGGL(vt_prep_kernel, dim3(1280), block, 0, stream, V, Vt);
        hipLaunchKernelGGL((cantor_partial3_kernel<true>), grid, block, 0, stream,
                           Q, K, Vt, betas, tempr, fuse, (void*)out, R);
    }
}

// Round 21
// 54.771 us; speedup vs baseline: 4.2673x; 1.0306x over previous
//
#include <hip/hip_runtime.h>
#include <math.h>

#define NDIR 5
#define E_ 16
#define W_ 3
#define D_ 128
#define P_ 256
#define B_ 4
#define ROWS 64
#define NPQ 4
#define NT 12        // k64-chunks: W_*P_/64
#define PARTN (B_ * E_ * NPQ * ROWS * D_)   // 2,097,152 elements per x-slice

typedef __attribute__((ext_vector_type(8))) short short8;
typedef __attribute__((ext_vector_type(4))) float f32x4;
typedef __attribute__((ext_vector_type(8))) float f32x8;
typedef __attribute__((ext_vector_type(4))) _Float16 half4;

struct RoutesArg { int r[E_][W_]; };

// Replicates Python _cantor_coord + stable argsort route construction on host.
static RoutesArg make_routes() {
    float coords[E_];
    for (int i = 0; i < E_; ++i) {
        double x = (double)i / (double)(E_ - 1);
        if (x < 1e-6) x = 1e-6;
        if (x > 1.0 - 1e-6) x = 1.0 - 1e-6;
        double val = 0.0, factor = 0.5;
        for (int d = 0; d < 8; ++d) {
            x *= 3.0;
            int digit = (int)x;
            x -= (double)digit;
            if (digit == 2) val += factor;
            factor *= 0.5;
        }
        coords[i] = (float)val;
    }
    RoutesArg R;
    for (int i = 0; i < E_; ++i) {
        float d[E_]; int idx[E_];
        for (int j = 0; j < E_; ++j) { d[j] = fabsf(coords[j] - coords[i]); idx[j] = j; }
        for (int a = 1; a < E_; ++a) {
            int key = idx[a]; float kd = d[key];
            int c = a - 1;
            while (c >= 0 && d[idx[c]] > kd) { idx[c + 1] = idx[c]; --c; }
            idx[c + 1] = key;
        }
        int top[W_] = { idx[0], idx[1], idx[2] };
        if (top[0] > top[1]) { int t = top[0]; top[0] = top[1]; top[1] = t; }
        if (top[1] > top[2]) { int t = top[1]; top[1] = top[2]; top[2] = t; }
        if (top[0] > top[1]) { int t = top[0]; top[0] = top[1]; top[1] = t; }
        for (int w = 0; w < W_; ++w) R.r[i][w] = top[w];
    }
    return R;
}

// exact RNE float->bf16 (finite inputs only)
static __device__ __forceinline__ unsigned short f2bf(float f) {
    union { float f; unsigned int u; } v; v.f = f;
    unsigned int r = (v.u + 0x7FFFu + ((v.u >> 16) & 1u)) >> 16;
    return (unsigned short)r;
}

// HW packed f32->bf16 (RNE), proven correct in Rounds 6/7/12/13/16-20.
static __device__ __forceinline__ unsigned int cvt_pk_bf16(float lo, float hi) {
    unsigned int r;
    asm("v_cvt_pk_bf16_f32 %0, %1, %2" : "=v"(r) : "v"(lo), "v"(hi));
    return r;
}

// By-VALUE vector in, literal indices only -> stays in registers (rule #20).
static __device__ __forceinline__ short8 pack8(f32x8 a) {
    union { unsigned int u[4]; short8 s; } cv;
    cv.u[0] = cvt_pk_bf16(a[0], a[1]);
    cv.u[1] = cvt_pk_bf16(a[2], a[3]);
    cv.u[2] = cvt_pk_bf16(a[4], a[5]);
    cv.u[3] = cvt_pk_bf16(a[6], a[7]);
    return cv.s;
}

// async global->LDS, 16B per lane (dest = wave-uniform base + lane*16)
static __device__ __forceinline__ void gld16(const void* g, void* l) {
    __builtin_amdgcn_global_load_lds(
        (const __attribute__((address_space(1))) unsigned int*)g,
        (__attribute__((address_space(3))) unsigned int*)l,
        16, 0, 0);
}

// ---- prep: V fp32 [slab][k=256][f=128] -> Vt bf16 [slab][f=128][k=256] ----
// LDS-tiled transpose: both global read and write are 16B/lane coalesced.
__global__ __launch_bounds__(256) void vt_prep_kernel(
    const float* __restrict__ V, unsigned short* __restrict__ Vt)
{
    __shared__ unsigned short tl[32][80];   // [f][k64], stride 160B (16B-mult)

    const int slab = blockIdx.x >> 2;       // 0..319
    const int kq   = blockIdx.x & 3;        // k-quarter (64 k's)
    const int tid  = threadIdx.x;

    const float* src = V + (size_t)slab * (P_ * D_) + (size_t)(kq * 64) * D_;
    unsigned short* dst = Vt + (size_t)slab * (P_ * D_) + kq * 64;

    #pragma unroll
    for (int ft = 0; ft < 4; ++ft) {
        const int f0 = ft * 32;
        if (ft) __syncthreads();   // protect tl from previous read phase
        #pragma unroll
        for (int it = 0; it < 2; ++it) {
            const int idx = it * 256 + tid;
            const int kk  = idx >> 3;        // 0..63
            const int fg  = idx & 7;         // float4 group within 32 f
            const float4 v = *reinterpret_cast<const float4*>(
                src + (size_t)kk * D_ + f0 + fg * 4);
            tl[fg * 4 + 0][kk] = f2bf(v.x);
            tl[fg * 4 + 1][kk] = f2bf(v.y);
            tl[fg * 4 + 2][kk] = f2bf(v.z);
            tl[fg * 4 + 3][kk] = f2bf(v.w);
        }
        __syncthreads();
        {
            const int f  = tid >> 3;         // 0..31
            const int kg = tid & 7;          // 16B group of k
            const uint4 val = *reinterpret_cast<const uint4*>(&tl[f][kg * 8]);
            *reinterpret_cast<uint4*>(&dst[(size_t)(f0 + f) * P_ + kg * 8]) = val;
        }
    }
}

// Block = (x, e, b, pq-tile of 64 rows); 1280 blocks, 4 waves, 2x2 wave split
// (32-row half x 64-col half). Vt k64-tiles staged via global_load_lds into a
// DOUBLE-buffered 2x16KB LDS region (XOR-swizzled source, zero bank conflicts).
//
// T3/T4 pipeline (new, m218): 2-deep prefetch with RAW s_barrier + COUNTED
// s_waitcnt vmcnt(4) — never vmcnt(0) in the main loop. R17/19/20 all used
// __syncthreads(), whose implicit vmcnt(0) drains the JUST-issued stage loads
// (full L2/L3 latency, ~11x per block) -> partial3 stuck at 41us, VALUBusy 49%.
// Here the wait at chunk t covers loads issued at chunk t-1 (one full chunk
// of compute ago); the 4 newest loads stay in flight across the barrier.
// Wait arithmetic: 4 gld16/stage, <=2 stages outstanding -> vmcnt(4) ==
// "oldest stage landed". Last two iterations degrade to vmcnt(0)/no-stage.
template <bool ATOMIC>
__global__ __launch_bounds__(256, 4) void cantor_partial3_kernel(
    const float* __restrict__ Q, const float* __restrict__ K,
    const unsigned short* __restrict__ Vt, const float* __restrict__ betas,
    const float* __restrict__ temperature, const float* __restrict__ fusion,
    void* __restrict__ target, RoutesArg routes)
{
    __shared__ float s_lds[W_ * P_];                         // 3 KB
    __shared__ __align__(16) unsigned char vbuf[2][16384];   // 32 KB dbuf

    // XCD-bijective swizzle: 1280 blocks = 8 XCDs x 160
    const int orig = blockIdx.x;
    const int wg   = (orig & 7) * 160 + (orig >> 3);

    const int pq = wg & 3;
    const int b  = (wg >> 2) & 3;
    const int e  = (wg >> 4) & 15;
    const int x  = wg >> 8;

    const int tid  = threadIdx.x;
    const int lane = tid & 63;
    const int wv   = tid >> 6;
    const int l15  = lane & 15;
    const int lg   = lane >> 4;

    const int rowbase = (wv >> 1) * 32;   // wave's 32-row half
    const int fhalf   = wv & 1;           // wave's 64-col half

    const float temp = fabsf(temperature[0]) + 1e-6f;

    // fusion softmax -> weight for this x
    float fwx;
    {
        float fv[NDIR], fmx = -1e30f, fsum = 0.f;
        #pragma unroll
        for (int i = 0; i < NDIR; ++i) { fv[i] = fusion[i]; fmx = fmaxf(fmx, fv[i]); }
        #pragma unroll
        for (int i = 0; i < NDIR; ++i) { fv[i] = __expf(fv[i] - fmx); fsum += fv[i]; }
        fwx = fv[x] / fsum;
    }

    int rt[W_]; float bf3[W_];
    #pragma unroll
    for (int w = 0; w < W_; ++w) {
        rt[w] = routes.r[e][w];
        float bv_ = betas[e * E_ + rt[w]];
        bf3[w] = (rt[w] == e) ? 1.0f : 1.0f / (1.0f + __expf(-bv_));
    }

    // stage s = K * beta (768 floats)
    #pragma unroll
    for (int w = 0; w < W_; ++w)
        s_lds[w * P_ + tid] =
            K[(((size_t)(x * E_ + rt[w])) * B_ + b) * P_ + tid] * bf3[w];

    // q rows this lane contributes to
    const float* Qb = Q + (((size_t)(x * E_ + e)) * B_ + b) * P_ + pq * ROWS + rowbase;
    float q2[2];
    q2[0] = Qb[l15] / temp;
    q2[1] = Qb[16 + l15] / temp;

    // Vt slab pointers (bf16 units)
    const unsigned short* vs0 = Vt + ((size_t)(x * E_ + rt[0]) * B_ + b) * (P_ * D_);
    const unsigned short* vs1 = Vt + ((size_t)(x * E_ + rt[1]) * B_ + b) * (P_ * D_);
    const unsigned short* vs2 = Vt + ((size_t)(x * E_ + rt[2]) * B_ + b) * (P_ * D_);

    // ---- stage addressing (R17-proven, zero conflicts) ----
    // lane covers f = wv*8 + (lane>>3) + h*32, 16B chunk j = lane&7;
    // source k-chunk = j ^ (lane>>3)  (inverse-swizzle so LDS is swizzled);
    // dest (wave-uniform) = vbuf[bi] + wv*1024 + h*4096, HW adds lane*16.
    const int src_off = (wv * 8 + (lane >> 3)) * P_ + ((lane & 7) ^ (lane >> 3)) * 8;

    // ---- read addressing: byte = f*128 + ((s*4+lg)^(f&7))*16, f = c'*16+l15 ----
    const int rdbase = fhalf * 8192 + l15 * 128 + ((lg ^ (l15 & 7)) * 16);

    #define STAGE(bi, t_) do {                                                   \
        const unsigned short* sl_ = ((t_) >> 2) == 0 ? vs0                       \
                                  : (((t_) >> 2) == 1 ? vs1 : vs2);              \
        const unsigned short* sb_ = sl_ + (((t_) & 3) * 64) + src_off;           \
        char* db_ = (char*)vbuf[bi] + wv * 1024;                                 \
        gld16(sb_,          db_);                                                \
        gld16(sb_ +  8192,  db_ + 4096);                                         \
        gld16(sb_ + 16384,  db_ + 8192);                                         \
        gld16(sb_ + 24576,  db_ + 12288);                                        \
    } while (0)

    STAGE(0, 0);
    STAGE(1, 1);
    __syncthreads();   // prologue: drains everything; s_lds + buf0 + buf1 ready

    f32x4 acc[2][4];
    #pragma unroll
    for (int fr = 0; fr < 2; ++fr)
        #pragma unroll
        for (int c = 0; c < 4; ++c)
            acc[fr][c] = (f32x4){0.f, 0.f, 0.f, 0.f};
    float den[2] = {0.f, 0.f};

    #pragma unroll 1   // R16 lesson: full unroll -> VGPR blowup -> 1 block/CU
    for (int t = 0; t < NT; ++t) {
        const int cur = t & 1;

        #pragma unroll
        for (int s = 0; s < 2; ++s) {
            // ---- A fragments: 16 exps (s octet broadcast from s_lds) ----
            const float* sp = s_lds + (t >> 2) * P_ + (t & 3) * 64 + s * 32 + 8 * lg;
            f32x8 sv;
            {
                const float4 s0_ = *reinterpret_cast<const float4*>(sp);
                const float4 s1_ = *reinterpret_cast<const float4*>(sp + 4);
                sv[0] = s0_.x; sv[1] = s0_.y; sv[2] = s0_.z; sv[3] = s0_.w;
                sv[4] = s1_.x; sv[5] = s1_.y; sv[6] = s1_.z; sv[7] = s1_.w;
            }
            short8 af0, af1;
            {
                f32x8 e0, e1;
                #pragma unroll
                for (int i = 0; i < 8; ++i) e0[i] = __expf(q2[0] * sv[i]);
                #pragma unroll
                for (int i = 0; i < 8; ++i) e1[i] = __expf(q2[1] * sv[i]);
                den[0] += ((e0[0]+e0[1]) + (e0[2]+e0[3])) + ((e0[4]+e0[5]) + (e0[6]+e0[7]));
                den[1] += ((e1[0]+e1[1]) + (e1[2]+e1[3])) + ((e1[4]+e1[5]) + (e1[6]+e1[7]));
                af0 = pack8(e0);
                af1 = pack8(e1);
            }

            // ---- 4 col-groups: swizzled ds_read_b128 + 2 MFMAs each ----
            #pragma unroll
            for (int c = 0; c < 4; ++c) {
                const short8 bf = *reinterpret_cast<const short8*>(
                    &vbuf[cur][(rdbase ^ (s << 6)) + c * 2048]);
                acc[0][c] = __builtin_amdgcn_mfma_f32_16x16x32_bf16(
                    af0, bf, acc[0][c], 0, 0, 0);
                acc[1][c] = __builtin_amdgcn_mfma_f32_16x16x32_bf16(
                    af1, bf, acc[1][c], 0, 0, 0);
            }
        }

        // ---- T3/T4 sync tail: raw barriers + counted vmcnt ----
        __builtin_amdgcn_s_barrier();          // all waves done reading vbuf[cur]
        if (t + 2 < NT) STAGE(cur, t + 2);     // refill freed buffer; stays in flight
        if (t + 1 < NT) {
            if (t + 2 < NT) {
                asm volatile("s_waitcnt vmcnt(4)" ::: "memory");  // stage(t+1) landed
            } else {
                asm volatile("s_waitcnt vmcnt(0)" ::: "memory");  // final drain
            }
            __builtin_amdgcn_s_barrier();      // vbuf[(t+1)&1] visible to all waves
        }
    }
    #undef STAGE

    // ---- full-row denominators: sum across the 4 lane-groups ----
    #pragma unroll
    for (int fr = 0; fr < 2; ++fr) {
        den[fr] += __shfl_xor(den[fr], 16);
        den[fr] += __shfl_xor(den[fr], 32);
    }

    // ---- scale + write ----
    const size_t obase = ((((size_t)b * E_ + e) * NPQ) + pq) * (ROWS * D_);

    #pragma unroll
    for (int fr = 0; fr < 2; ++fr) {
        #pragma unroll
        for (int r = 0; r < 4; ++r) {
            const float dr = __shfl(den[fr], 4 * lg + r);   // den of row fr*16+4*lg+r
            const float sc = fwx / dr;
            const int row = rowbase + fr * 16 + 4 * lg + r;
            const size_t off = obase + (size_t)row * D_ + fhalf * 64;
            #pragma unroll
            for (int c = 0; c < 4; ++c) {
                const float v = sc * acc[fr][c][r];
                if (ATOMIC) {
                    atomicAdd((float*)target + off + c * 16 + l15, v);
                } else {
                    _Float16* op = (_Float16*)target + (size_t)x * PARTN + off;
                    op[c * 16 + l15] = (_Float16)v;
                }
            }
        }
    }
}

// sum 5 fp16 partial slices -> fp32 out
__global__ __launch_bounds__(256) void reduce5h_kernel(
    const _Float16* __restrict__ part, float* __restrict__ out)
{
    const size_t i = (size_t)blockIdx.x * 256 + threadIdx.x;   // 4-elem group
    float a0 = 0.f, a1 = 0.f, a2 = 0.f, a3 = 0.f;
    #pragma unroll
    for (int x = 0; x < NDIR; ++x) {
        const half4 h = *reinterpret_cast<const half4*>(part + (size_t)x * PARTN + i * 4);
        a0 += (float)h[0]; a1 += (float)h[1]; a2 += (float)h[2]; a3 += (float)h[3];
    }
    reinterpret_cast<float4*>(out)[i] = make_float4(a0, a1, a2, a3);
}

extern "C" void kernel_launch(void* const* d_in, const int* in_sizes, int n_in,
                              void* d_out, int out_size, void* d_ws, size_t ws_size,
                              hipStream_t stream) {
    (void)in_sizes; (void)n_in;
    RoutesArg R = make_routes();
    const float* Q     = (const float*)d_in[0];
    const float* K     = (const float*)d_in[1];
    const float* V     = (const float*)d_in[2];
    const float* betas = (const float*)d_in[3];
    const float* tempr = (const float*)d_in[4];
    const float* fuse  = (const float*)d_in[5];
    float* out = (float*)d_out;

    const size_t vt_bytes   = (size_t)NDIR * E_ * B_ * P_ * D_ * 2;   // ~21 MB
    const size_t part_bytes = (size_t)NDIR * PARTN * 2;               // ~21 MB (fp16)

    dim3 grid(NDIR * E_ * B_ * NPQ);   // 1280
    dim3 block(256);

    if (ws_size >= vt_bytes + part_bytes) {
        unsigned short* Vt = (unsigned short*)d_ws;
        _Float16* part = (_Float16*)((char*)d_ws + vt_bytes);
        hipLaunchKernelGGL(vt_prep_kernel, dim3(1280), block, 0, stream, V, Vt);
        hipLaunchKernelGGL((cantor_partial3_kernel<false>), grid, block, 0, stream,
                           Q, K, Vt, betas, tempr, fuse, (void*)part, R);
        hipLaunchKernelGGL(reduce5h_kernel, dim3(2048), block, 0, stream,
                           part, out);
    } else {
        unsigned short* Vt = (unsigned short*)d_ws;   // ws >= 21MB always observed
        (void)hipMemsetAsync(d_out, 0, (size_t)out_size * 4, stream);
        hipLaunchKernelGGL(vt_prep_kernel, dim3(1280), block, 0, stream, V, Vt);
        hipLaunchKernelGGL((cantor_partial3_kernel<true>), grid, block, 0, stream,
                           Q, K, Vt, betas, tempr, fuse, (void*)out, R);
    }
}